// Round 11
// baseline (96.563 us; speedup 1.0000x reference)
//
#include <hip/hip_runtime.h>

#define KDIM 1024
#define NDIM 16384
#define CHUNKS 256
#define CLEN 64   // NDIM / CHUNKS
#define KT32 32   // KDIM / 32

typedef __bf16 bf16_t;
typedef bf16_t bf16x8 __attribute__((ext_vector_type(8)));
typedef bf16_t bf16x4 __attribute__((ext_vector_type(4)));
typedef float f32x4 __attribute__((ext_vector_type(4)));

__device__ __forceinline__ void gload_lds16(const bf16_t* g, bf16_t* l) {
  __builtin_amdgcn_global_load_lds(
      (const __attribute__((address_space(1))) void*)g,
      (__attribute__((address_space(3))) void*)l, 16, 0, 0);
}

// ---------------- fused: scan phase1 (coalesced, one row/block) + prefix + obs->u8 + hmu
//                  blocks >= 1024: halpha fp32->bf16 convert ----------------
__global__ __launch_bounds__(256) void k_phase1(const float* __restrict__ obs,
                                                const float* __restrict__ hbeta,
                                                float* __restrict__ carry,
                                                float* __restrict__ hmu,
                                                const float* __restrict__ A,
                                                bf16_t* __restrict__ Ab,
                                                unsigned char* __restrict__ obs8) {
  if (blockIdx.x >= 1024) {
    size_t i = ((size_t)(blockIdx.x - 1024) * 256 + threadIdx.x) * 4;
    float4 v = *reinterpret_cast<const float4*>(A + i);
    bf16x4 o;
    o[0] = (bf16_t)v.x; o[1] = (bf16_t)v.y; o[2] = (bf16_t)v.z; o[3] = (bf16_t)v.w;
    *reinterpret_cast<bf16x4*>(Ab + i) = o;
    return;
  }
  __shared__ unsigned char s8[256][68];   // bank (17c + t/4)%32: 2-way max (free)
  __shared__ float sm[256], sa[256];
  __shared__ float wred[4];
  int tid = threadIdx.x;
  int k = blockIdx.x;                     // one obs row per block
  float beta = hbeta[0];
  float decay = expf(-beta);
  const float* p = obs + (size_t)k * NDIM;
  unsigned char* po = obs8 + (size_t)k * NDIM;
  float sum = 0.f;
#pragma unroll
  for (int w = 0; w < 16; ++w) {
    float4 v = *reinterpret_cast<const float4*>(p + w * 1024 + tid * 4);
    sum += v.x + v.y + v.z + v.w;
    uchar4 u;
    u.x = (unsigned char)v.x; u.y = (unsigned char)v.y;
    u.z = (unsigned char)v.z; u.w = (unsigned char)v.w;
    *reinterpret_cast<uchar4*>(po + w * 1024 + tid * 4) = u;          // coalesced
    int c = w * 16 + (tid >> 4), t = 4 * (tid & 15);
    *reinterpret_cast<uchar4*>(&s8[c][t]) = u;
  }
  __syncthreads();
  float S = 0.f;
#pragma unroll 8
  for (int t = 0; t < CLEN; ++t)
    S = decay * (S + beta * (float)s8[tid][t]);
  float dL = expf(-beta * (float)CLEN);
  sm[tid] = dL; sa[tid] = S;
  __syncthreads();
#pragma unroll
  for (int s = 1; s < 256; s <<= 1) {
    float mp = 0.f, ap = 0.f;
    bool act = (tid >= s);
    if (act) { mp = sm[tid - s]; ap = sa[tid - s]; }
    __syncthreads();
    if (act) { sa[tid] += sm[tid] * ap; sm[tid] *= mp; }
    __syncthreads();
  }
  carry[(size_t)k * CHUNKS + tid] = (tid == 0) ? 0.f : sa[tid - 1];   // exclusive
  sum += __shfl_down(sum, 32); sum += __shfl_down(sum, 16);
  sum += __shfl_down(sum, 8);  sum += __shfl_down(sum, 4);
  sum += __shfl_down(sum, 2);  sum += __shfl_down(sum, 1);
  if ((tid & 63) == 0) wred[tid >> 6] = sum;
  __syncthreads();
  if (tid == 0)
    hmu[k] = (wred[0] + wred[1] + wred[2] + wred[3]) * (1.0f / NDIM) * 0.1f + 0.01f;
}

// ---------------- scan phase 3: full scan with carry (obs8 input), write S_all [t][j] bf16 ----------------
__global__ __launch_bounds__(64) void k_phase3(const unsigned char* __restrict__ obs8,
                                               const float* __restrict__ hbeta,
                                               const float* __restrict__ carry,
                                               bf16_t* __restrict__ S_all) {
  int c  = blockIdx.x & (CHUNKS - 1);
  int kb = blockIdx.x >> 8;
  int lane = threadIdx.x;
  float beta = hbeta[0];
  float decay = expf(-beta);
  __shared__ unsigned char s8[64][68];
  __shared__ bf16_t out_s[64][72];
  int k0 = kb * 64, t0 = c * CLEN;
  const unsigned char* base = obs8 + (size_t)k0 * NDIM + t0;
#pragma unroll 4
  for (int w = 0; w < 16; ++w) {
    int r = w * 4 + (lane >> 4), col = (lane & 15) * 4;
    *reinterpret_cast<uchar4*>(&s8[r][col]) =
        *reinterpret_cast<const uchar4*>(base + (size_t)r * NDIM + col);
  }
  __syncthreads();
  float S = carry[(size_t)(k0 + lane) * CHUNKS + c];
#pragma unroll 8
  for (int t = 0; t < CLEN; ++t) {
    out_s[t][lane] = (bf16_t)S;
    S = decay * (S + beta * (float)s8[lane][t]);
  }
  __syncthreads();
#pragma unroll 4
  for (int t = 0; t < CLEN; ++t)
    S_all[(size_t)(t0 + t) * KDIM + k0 + lane] = out_s[t][lane];
}

// ---------------- GEMM lam1 = halpha @ S_all^T, fused softplus + loglik ----------------
// 128Mx256N tile, BK=32, 512 threads (8 waves, 2Mx4N -> 64x64/wave). LDS dbuf
// 48KB -> TWO blocks/CU (96KB, 16 waves/CU): two independent barrier groups per
// CU hide each other's barrier/lgkm stalls (the invariant all 1-block/CU
// schedules were missing). 2 barriers/tile, counted vmcnt(3), setprio on MFMA.
// BK=32 swizzle: slot ^= (row>>1)&3 -> 2-way max at 16-lane b128 granularity
// (free); applied on pre-swizzled GLOBAL source + swizzled ds_read (rule #21).
__global__ __launch_bounds__(512, 4) void k_gemm(const bf16_t* __restrict__ Ab,
                                                 const bf16_t* __restrict__ Bb,
                                                 const float* __restrict__ hmu,
                                                 const unsigned char* __restrict__ obs8,
                                                 float* __restrict__ out) {
  __shared__ bf16_t As[2][128 * 32];
  __shared__ bf16_t Bs[2][256 * 32];
  int tid = threadIdx.x;
  // XCD-chunk swizzle: 512 blocks, 8 XCDs, bijective; kb-fastest so the 8 blocks
  // sharing an S-panel (tb) sit on one XCD (panel fetched from HBM once).
  int b = blockIdx.x;
  int lb = (b & 7) * 64 + (b >> 3);
  int kb = lb & 7;            // M-tile (8)
  int tb = lb >> 3;           // N-tile (64)
  int lane = tid & 63, wid = tid >> 6;
  int wm = wid >> 2, wn = wid & 3;          // 2x4 waves, each 64x64 output
  int r15 = lane & 15, h = lane >> 4;
  f32x4 acc[4][4] = {};

  // staging source, pre-swizzled: sl = sp ^ ((row>>1)&3)
  int rA = tid >> 2, spA = tid & 3;
  const bf16_t* gA0 = Ab + (size_t)(kb * 128 + rA) * KDIM + (spA ^ ((rA >> 1) & 3)) * 8;
  const bf16_t* gB0;
  const bf16_t* gB1;
  {
    int r0 = tid >> 2, sp = tid & 3;
    gB0 = Bb + (size_t)(tb * 256 + r0) * KDIM + (sp ^ ((r0 >> 1) & 3)) * 8;
    int r1 = (512 + tid) >> 2;
    gB1 = Bb + (size_t)(tb * 256 + r1) * KDIM + (sp ^ ((r1 >> 1) & 3)) * 8;
  }

#define STAGE(buf, kk) do { \
  gload_lds16(gA0 + (kk), &As[buf][(wid * 64) * 8]); \
  gload_lds16(gB0 + (kk), &Bs[buf][(wid * 64) * 8]); \
  gload_lds16(gB1 + (kk), &Bs[buf][(512 + wid * 64) * 8]); \
} while (0)

  // fragment reads, swizzled: elem = row*32 + ((h ^ ((row>>1)&3)) * 8)
#define AF(buf, mi) (*reinterpret_cast<const bf16x8*>( \
    &As[buf][(wm * 64 + (mi) * 16 + r15) * 32 + ((h ^ (((wm * 64 + (mi) * 16 + r15) >> 1) & 3)) * 8)]))
#define BF(buf, ni) (*reinterpret_cast<const bf16x8*>( \
    &Bs[buf][(wn * 64 + (ni) * 16 + r15) * 32 + ((h ^ (((wn * 64 + (ni) * 16 + r15) >> 1) & 3)) * 8)]))

  STAGE(0, 0);   // tile 0 in flight (3 loads)

  int cur = 0;
  for (int t = 0; t < KT32; ++t) {
    __builtin_amdgcn_sched_barrier(0);       // pin prev tile's ds_reads above barrier (a)
    __builtin_amdgcn_s_barrier();            // (a) all waves done reading buf^1
    if (t < KT32 - 1) {
      STAGE(cur ^ 1, (t + 1) * 32);          // 3 loads into freed buf^1
      asm volatile("s_waitcnt vmcnt(3)" ::: "memory");  // tile t's 3 retired
    } else {
      asm volatile("s_waitcnt vmcnt(0)" ::: "memory");
    }
    __builtin_amdgcn_s_barrier();            // (b) buf[cur] valid

    bf16x8 a[4], bv[4];
#pragma unroll
    for (int m = 0; m < 4; ++m) a[m] = AF(cur, m);
#pragma unroll
    for (int n = 0; n < 4; ++n) bv[n] = BF(cur, n);
    __builtin_amdgcn_s_setprio(1);
#pragma unroll
    for (int m = 0; m < 4; ++m)
#pragma unroll
      for (int n = 0; n < 4; ++n)
        acc[m][n] = __builtin_amdgcn_mfma_f32_16x16x32_bf16(a[m], bv[n], acc[m][n], 0, 0, 0);
    __builtin_amdgcn_s_setprio(0);
    cur ^= 1;
  }
#undef STAGE
#undef AF
#undef BF

  // epilogue: lams = softplus(hmu + lam1); loglik partial = obs*log(lams) - lams
  float lsum = 0.f;
  float* lams = out + 1;
#pragma unroll
  for (int mi = 0; mi < 4; ++mi) {
    int krow0 = kb * 128 + wm * 64 + mi * 16 + h * 4;
#pragma unroll
    for (int ni = 0; ni < 4; ++ni) {
      int t = tb * 256 + wn * 64 + ni * 16 + r15;
#pragma unroll
      for (int r = 0; r < 4; ++r) {
        int krow = krow0 + r;
        float x = hmu[krow] + acc[mi][ni][r];
        float lam = fmaxf(x, 0.f) + __logf(1.f + __expf(-fabsf(x)));
        lams[(size_t)krow * NDIM + t] = lam;
        float o = (float)obs8[(size_t)krow * NDIM + t];
        lsum += o * __logf(lam) - lam;
      }
    }
  }
  lsum += __shfl_down(lsum, 32);
  lsum += __shfl_down(lsum, 16);
  lsum += __shfl_down(lsum, 8);
  lsum += __shfl_down(lsum, 4);
  lsum += __shfl_down(lsum, 2);
  lsum += __shfl_down(lsum, 1);
  __shared__ float wsum[8];
  if (lane == 0) wsum[wid] = lsum;
  __syncthreads();
  if (tid == 0) {
    float s = 0.f;
#pragma unroll
    for (int w = 0; w < 8; ++w) s += wsum[w];
    atomicAdd(out, s);
  }
}

extern "C" void kernel_launch(void* const* d_in, const int* in_sizes, int n_in,
                              void* d_out, int out_size, void* d_ws, size_t ws_size,
                              hipStream_t stream) {
  const float* obs    = (const float*)d_in[0];
  const float* halpha = (const float*)d_in[1];
  const float* hbeta  = (const float*)d_in[2];
  float* out = (float*)d_out;

  char* ws = (char*)d_ws;
  bf16_t* S_all = (bf16_t*)ws;                                   // 32 MB, [NDIM][KDIM]
  float*  carry = (float*)(ws + (size_t)NDIM * KDIM * 2);        // 1 MB, [K][CHUNKS]
  float*  hmu   = carry + (size_t)KDIM * CHUNKS;                 // 4 KB
  bf16_t* Ab    = (bf16_t*)(hmu + KDIM);                         // 2 MB
  unsigned char* obs8 = (unsigned char*)(Ab + (size_t)KDIM * KDIM);  // 16.8 MB

  hipMemsetAsync(d_out, 0, sizeof(float), stream);               // loglik accumulator
  k_phase1<<<2048, 256, 0, stream>>>(obs, hbeta, carry, hmu, halpha, Ab, obs8);
  k_phase3<<<(KDIM / 64) * CHUNKS, 64, 0, stream>>>(obs8, hbeta, carry, S_all);
  k_gemm<<<8 * (NDIM / 256), 512, 0, stream>>>(Ab, S_all, hmu, obs8, out);
}

// Round 12
// 91.883 us; speedup vs baseline: 1.0509x; 1.0509x over previous
//
#include <hip/hip_runtime.h>

#define KDIM 1024
#define NDIM 16384
#define CHUNKS 256
#define CLEN 64   // NDIM / CHUNKS
#define KTILES 16 // KDIM / 64

typedef __bf16 bf16_t;
typedef bf16_t bf16x8 __attribute__((ext_vector_type(8)));
typedef bf16_t bf16x4 __attribute__((ext_vector_type(4)));
typedef float f32x4 __attribute__((ext_vector_type(4)));

__device__ __forceinline__ void gload_lds16(const bf16_t* g, bf16_t* l) {
  __builtin_amdgcn_global_load_lds(
      (const __attribute__((address_space(1))) void*)g,
      (__attribute__((address_space(3))) void*)l, 16, 0, 0);
}

// ---------------- fused: scan phase1 (coalesced, one row/block) + shuffle-prefix + obs->u8 + hmu
//                  blocks >= 1024: halpha fp32->bf16 convert ----------------
__global__ __launch_bounds__(256) void k_phase1(const float* __restrict__ obs,
                                                const float* __restrict__ hbeta,
                                                float* __restrict__ carry,
                                                float* __restrict__ hmu,
                                                const float* __restrict__ A,
                                                bf16_t* __restrict__ Ab,
                                                unsigned char* __restrict__ obs8) {
  if (blockIdx.x >= 1024) {
    size_t i = ((size_t)(blockIdx.x - 1024) * 256 + threadIdx.x) * 4;
    float4 v = *reinterpret_cast<const float4*>(A + i);
    bf16x4 o;
    o[0] = (bf16_t)v.x; o[1] = (bf16_t)v.y; o[2] = (bf16_t)v.z; o[3] = (bf16_t)v.w;
    *reinterpret_cast<bf16x4*>(Ab + i) = o;
    return;
  }
  __shared__ unsigned char s8[256][68];   // bank (17c + t/4)%32: 2-way max (free)
  __shared__ float wm_lds[4], wa_lds[4], wsum_lds[4];
  int tid = threadIdx.x;
  int lane = tid & 63, wid = tid >> 6;
  int k = blockIdx.x;                     // one obs row per block
  float beta = hbeta[0];
  float decay = expf(-beta);
  const float* p = obs + (size_t)k * NDIM;
  unsigned char* po = obs8 + (size_t)k * NDIM;
  float sum = 0.f;
#pragma unroll
  for (int w = 0; w < 16; ++w) {
    float4 v = *reinterpret_cast<const float4*>(p + w * 1024 + tid * 4);
    sum += v.x + v.y + v.z + v.w;
    uchar4 u;
    u.x = (unsigned char)v.x; u.y = (unsigned char)v.y;
    u.z = (unsigned char)v.z; u.w = (unsigned char)v.w;
    *reinterpret_cast<uchar4*>(po + w * 1024 + tid * 4) = u;          // coalesced
    int c = w * 16 + (tid >> 4), t = 4 * (tid & 15);
    *reinterpret_cast<uchar4*>(&s8[c][t]) = u;
  }
  __syncthreads();
  // per-thread chunk-local scan (chunk c = tid); all chunks share multiplier dL
  float S = 0.f;
#pragma unroll 8
  for (int t = 0; t < CLEN; ++t)
    S = decay * (S + beta * (float)s8[tid][t]);
  float dL = expf(-beta * (float)CLEN);
  // wave-level inclusive affine scan via shuffles: state f(x) = m*x + a
  float m = dL, a = S;
#pragma unroll
  for (int off = 1; off < 64; off <<= 1) {
    float mp = __shfl_up(m, off);
    float ap = __shfl_up(a, off);
    if (lane >= off) { a = a + m * ap; m = m * mp; }
  }
  // wave totals -> LDS (single barrier), plus hmu partial sums
  float ws = sum;
  ws += __shfl_down(ws, 32); ws += __shfl_down(ws, 16);
  ws += __shfl_down(ws, 8);  ws += __shfl_down(ws, 4);
  ws += __shfl_down(ws, 2);  ws += __shfl_down(ws, 1);
  if (lane == 63) { wm_lds[wid] = m; wa_lds[wid] = a; }
  if (lane == 0)  wsum_lds[wid] = ws;
  __syncthreads();
  // exclusive wave prefix (applied to x=0 -> just the additive part), tiny serial
  float Aw = 0.f;
#pragma unroll
  for (int w = 0; w < 4; ++w) {
    if (w == wid) break;
    Aw = wa_lds[w] + wm_lds[w] * Aw;   // compose: this wave after previous
  }
  // exclusive within wave: shift inclusive by 1
  float me = __shfl_up(m, 1), ae = __shfl_up(a, 1);
  if (lane == 0) { me = 1.f; ae = 0.f; }
  // carry for chunk c = (lane-exclusive) applied after wave-exclusive, from x=0
  carry[(size_t)k * CHUNKS + tid] = ae + me * Aw;
  if (tid == 0)
    hmu[k] = (wsum_lds[0] + wsum_lds[1] + wsum_lds[2] + wsum_lds[3]) * (1.0f / NDIM) * 0.1f + 0.01f;
}

// ---------------- scan phase 3: full scan with carry (obs8 input), write S_all [t][j] bf16 ----------------
__global__ __launch_bounds__(64) void k_phase3(const unsigned char* __restrict__ obs8,
                                               const float* __restrict__ hbeta,
                                               const float* __restrict__ carry,
                                               bf16_t* __restrict__ S_all) {
  int c  = blockIdx.x & (CHUNKS - 1);
  int kb = blockIdx.x >> 8;
  int lane = threadIdx.x;
  float beta = hbeta[0];
  float decay = expf(-beta);
  __shared__ unsigned char s8[64][68];
  __shared__ bf16_t out_s[64][72];
  int k0 = kb * 64, t0 = c * CLEN;
  const unsigned char* base = obs8 + (size_t)k0 * NDIM + t0;
#pragma unroll 4
  for (int w = 0; w < 16; ++w) {
    int r = w * 4 + (lane >> 4), col = (lane & 15) * 4;
    *reinterpret_cast<uchar4*>(&s8[r][col]) =
        *reinterpret_cast<const uchar4*>(base + (size_t)r * NDIM + col);
  }
  __syncthreads();
  float S = carry[(size_t)(k0 + lane) * CHUNKS + c];
#pragma unroll 8
  for (int t = 0; t < CLEN; ++t) {
    out_s[t][lane] = (bf16_t)S;
    S = decay * (S + beta * (float)s8[lane][t]);
  }
  __syncthreads();
#pragma unroll 4
  for (int t = 0; t < CLEN; ++t)
    S_all[(size_t)(t0 + t) * KDIM + k0 + lane] = out_s[t][lane];
}

// ---------------- GEMM lam1 = halpha @ S_all^T, fused softplus + loglik ----------------
// [r9-proven config: best of 6 structural variants, 68.5 us]
// 256x256 tile, BK=64, 512 threads (8 waves, 2Mx4N). 2 barriers/tile, counted
// vmcnt(4) mid-loop; STAGE_A at tile head, STAGE_B mid-tile. LDS XOR-swizzle via
// pre-swizzled GLOBAL source + swizzled ds_read. setprio on MFMA.
__global__ __launch_bounds__(512, 2) void k_gemm(const bf16_t* __restrict__ Ab,
                                                 const bf16_t* __restrict__ Bb,
                                                 const float* __restrict__ hmu,
                                                 const unsigned char* __restrict__ obs8,
                                                 float* __restrict__ out) {
  __shared__ bf16_t As[2][256 * 64];
  __shared__ bf16_t Bs[2][256 * 64];
  int tid = threadIdx.x;
  int b = blockIdx.x;
  int lb = (b & 7) * 32 + (b >> 3);
  int kb = lb & 3;            // M-tile (4)
  int tb = lb >> 2;           // N-tile (64)
  int lane = tid & 63, wid = tid >> 6;
  int wm = wid >> 2, wn = wid & 3;          // 2x4 waves, each 128x64 output
  int r15 = lane & 15, h = lane >> 4;
  f32x4 acc[8][4] = {};

  const bf16_t* gA[4];
  const bf16_t* gB[4];
#pragma unroll
  for (int i = 0; i < 4; ++i) {
    int slot = i * 512 + tid;
    int row = slot >> 3, sp = slot & 7;
    int sl = sp ^ (row & 7);
    gA[i] = Ab + (size_t)(kb * 256 + row) * KDIM + sl * 8;
    gB[i] = Bb + (size_t)(tb * 256 + row) * KDIM + sl * 8;
  }

#define STAGE_A(buf, kkoff) do { \
  _Pragma("unroll") \
  for (int i = 0; i < 4; ++i) \
    gload_lds16(gA[i] + (kkoff), &As[buf][(i * 512 + wid * 64) * 8]); \
} while (0)
#define STAGE_B(buf, kkoff) do { \
  _Pragma("unroll") \
  for (int i = 0; i < 4; ++i) \
    gload_lds16(gB[i] + (kkoff), &Bs[buf][(i * 512 + wid * 64) * 8]); \
} while (0)

#define A_FRAG(mi, sl) (*reinterpret_cast<const bf16x8*>( \
    &As[cur][(wm * 128 + (mi) * 16 + r15) * 64 + ((((sl)) ^ ((wm * 128 + (mi) * 16 + r15) & 7)) * 8)]))
#define B_FRAG(ni, sl) (*reinterpret_cast<const bf16x8*>( \
    &Bs[cur][(wn * 64 + (ni) * 16 + r15) * 64 + ((((sl)) ^ ((wn * 64 + (ni) * 16 + r15) & 7)) * 8)]))

  STAGE_A(0, 0);
  STAGE_B(0, 0);

  int cur = 0;
  for (int kt = 0; kt < KTILES; ++kt) {
    __builtin_amdgcn_sched_barrier(0);
    __builtin_amdgcn_s_barrier();            // (a) all waves done reading buf^1
    if (kt < KTILES - 1) {
      STAGE_A(cur ^ 1, (kt + 1) * 64);
      asm volatile("s_waitcnt vmcnt(4)" ::: "memory");
    } else {
      asm volatile("s_waitcnt vmcnt(0)" ::: "memory");
    }
    __builtin_amdgcn_s_barrier();            // (b) buf[cur] valid

    bf16x8 a0[4], a1[4], bf0[4];
#pragma unroll
    for (int m = 0; m < 4; ++m) a0[m] = A_FRAG(m, h);
#pragma unroll
    for (int n = 0; n < 4; ++n) bf0[n] = B_FRAG(n, h);
    __builtin_amdgcn_s_setprio(1);
#pragma unroll
    for (int m = 0; m < 4; ++m)
#pragma unroll
      for (int n = 0; n < 4; ++n)
        acc[m][n] = __builtin_amdgcn_mfma_f32_16x16x32_bf16(a0[m], bf0[n], acc[m][n], 0, 0, 0);
    __builtin_amdgcn_s_setprio(0);
#pragma unroll
    for (int m = 0; m < 4; ++m) a1[m] = A_FRAG(4 + m, h);
    __builtin_amdgcn_s_setprio(1);
#pragma unroll
    for (int m = 0; m < 4; ++m)
#pragma unroll
      for (int n = 0; n < 4; ++n)
        acc[4 + m][n] = __builtin_amdgcn_mfma_f32_16x16x32_bf16(a1[m], bf0[n], acc[4 + m][n], 0, 0, 0);
    __builtin_amdgcn_s_setprio(0);
    if (kt < KTILES - 1) STAGE_B(cur ^ 1, (kt + 1) * 64);
#pragma unroll
    for (int m = 0; m < 4; ++m) a0[m] = A_FRAG(m, 4 + h);
#pragma unroll
    for (int n = 0; n < 4; ++n) bf0[n] = B_FRAG(n, 4 + h);
    __builtin_amdgcn_s_setprio(1);
#pragma unroll
    for (int m = 0; m < 4; ++m)
#pragma unroll
      for (int n = 0; n < 4; ++n)
        acc[m][n] = __builtin_amdgcn_mfma_f32_16x16x32_bf16(a0[m], bf0[n], acc[m][n], 0, 0, 0);
    __builtin_amdgcn_s_setprio(0);
#pragma unroll
    for (int m = 0; m < 4; ++m) a1[m] = A_FRAG(4 + m, 4 + h);
    __builtin_amdgcn_s_setprio(1);
#pragma unroll
    for (int m = 0; m < 4; ++m)
#pragma unroll
      for (int n = 0; n < 4; ++n)
        acc[4 + m][n] = __builtin_amdgcn_mfma_f32_16x16x32_bf16(a1[m], bf0[n], acc[4 + m][n], 0, 0, 0);
    __builtin_amdgcn_s_setprio(0);
    cur ^= 1;
  }
#undef STAGE_A
#undef STAGE_B
#undef A_FRAG
#undef B_FRAG

  float lsum = 0.f;
  float* lams = out + 1;
#pragma unroll
  for (int mi = 0; mi < 8; ++mi) {
    int krow0 = kb * 256 + wm * 128 + mi * 16 + h * 4;
#pragma unroll
    for (int ni = 0; ni < 4; ++ni) {
      int t = tb * 256 + wn * 64 + ni * 16 + r15;
#pragma unroll
      for (int r = 0; r < 4; ++r) {
        int krow = krow0 + r;
        float x = hmu[krow] + acc[mi][ni][r];
        float lam = fmaxf(x, 0.f) + __logf(1.f + __expf(-fabsf(x)));
        lams[(size_t)krow * NDIM + t] = lam;
        float o = (float)obs8[(size_t)krow * NDIM + t];
        lsum += o * __logf(lam) - lam;
      }
    }
  }
  lsum += __shfl_down(lsum, 32);
  lsum += __shfl_down(lsum, 16);
  lsum += __shfl_down(lsum, 8);
  lsum += __shfl_down(lsum, 4);
  lsum += __shfl_down(lsum, 2);
  lsum += __shfl_down(lsum, 1);
  __shared__ float wsum[8];
  if (lane == 0) wsum[wid] = lsum;
  __syncthreads();
  if (tid == 0) {
    float s = 0.f;
#pragma unroll
    for (int w = 0; w < 8; ++w) s += wsum[w];
    atomicAdd(out, s);
  }
}

extern "C" void kernel_launch(void* const* d_in, const int* in_sizes, int n_in,
                              void* d_out, int out_size, void* d_ws, size_t ws_size,
                              hipStream_t stream) {
  const float* obs    = (const float*)d_in[0];
  const float* halpha = (const float*)d_in[1];
  const float* hbeta  = (const float*)d_in[2];
  float* out = (float*)d_out;

  char* ws = (char*)d_ws;
  bf16_t* S_all = (bf16_t*)ws;                                   // 32 MB, [NDIM][KDIM]
  float*  carry = (float*)(ws + (size_t)NDIM * KDIM * 2);        // 1 MB, [K][CHUNKS]
  float*  hmu   = carry + (size_t)KDIM * CHUNKS;                 // 4 KB
  bf16_t* Ab    = (bf16_t*)(hmu + KDIM);                         // 2 MB
  unsigned char* obs8 = (unsigned char*)(Ab + (size_t)KDIM * KDIM);  // 16.8 MB

  hipMemsetAsync(d_out, 0, sizeof(float), stream);               // loglik accumulator
  k_phase1<<<2048, 256, 0, stream>>>(obs, hbeta, carry, hmu, halpha, Ab, obs8);
  k_phase3<<<(KDIM / 64) * CHUNKS, 64, 0, stream>>>(obs8, hbeta, carry, S_all);
  k_gemm<<<4 * (NDIM / 256), 512, 0, stream>>>(Ab, S_all, hmu, obs8, out);
}